// Round 4
// baseline (27.256 us; speedup 1.0000x reference)
//
#include <hip/hip_runtime.h>

// AtomDistances: out[b,i,j] = mask[b,i]&&mask[b,j]&&(i!=j)
//                  ? 1/(safe_norm(pos[b,nbr[b,i,j]] - pos[b,i]) + 1e-8) : 0
// B=4, A=2048.
//
// R4: load-balance via per-batch row compaction (active rows first), so every
// wave owns exactly one row and heavy waves spread evenly over CUs. LDS
// positions packed as x (b32) + yz (b64) -> 8 gather instrs/chunk vs 12.
// Plain stores (L3 retains the output across replays). Depth-4 prefetch kept.

typedef float f4 __attribute__((ext_vector_type(4)));
typedef float f2 __attribute__((ext_vector_type(2)));

constexpr int A_DIM = 2048;
constexpr int WPB   = 8;          // rows (waves) per block
constexpr int NTHR  = WPB * 64;   // 512

// ---- prepass: per batch, compact active row ids to front, inactive to back
__global__ __launch_bounds__(512) void compact_rows_kernel(
    const int* __restrict__ mask, int* __restrict__ list) {
  const int b = blockIdx.x;
  const int* maskb = mask + (size_t)b * A_DIM;
  int* listb = list + (size_t)b * A_DIM;

  __shared__ int head, tail;
  if (threadIdx.x == 0) { head = 0; tail = A_DIM; }
  __syncthreads();

  const int lane = threadIdx.x & 63;
  for (int r = 0; r < A_DIM; r += 512) {
    const int row = r + threadIdx.x;
    const bool act = maskb[row] != 0;
    const unsigned long long bal = __ballot(act);
    const int na = __popcll(bal);
    int baseA = 0, baseI = 0;
    if (lane == 0) {
      baseA = atomicAdd(&head, na);
      baseI = atomicAdd(&tail, -(64 - na)) - (64 - na);
    }
    baseA = __shfl(baseA, 0);
    baseI = __shfl(baseI, 0);
    const int pa = __popcll(bal & ((1ull << lane) - 1ull));  // actives below me
    const int pi = lane - pa;                                // inactives below me
    if (act) listb[baseA + pa] = row;
    else     listb[baseI + pi] = row;
  }
}

// ---- main kernel: one row per wave, row id from compacted list
__global__ __launch_bounds__(NTHR, 8) void atom_distances_kernel(
    const float* __restrict__ pos,    // [B, A, 3]
    const int*   __restrict__ nbr,    // [B, A, A]
    const int*   __restrict__ mask,   // [B, A]
    const int*   __restrict__ list,   // [B, A] or nullptr
    float*       __restrict__ out) {  // [B, A, A]
  __shared__ float    sx[A_DIM];             // 8 KB
  __shared__ f2       syz[A_DIM];            // 16 KB
  __shared__ unsigned smaskbits[A_DIM / 32]; // 256 B

  const int blocks_per_b = A_DIM / WPB;      // 256
  const int b = blockIdx.x / blocks_per_b;
  const int s = blockIdx.x % blocks_per_b;

  const float* posb  = pos  + (size_t)b * A_DIM * 3;
  const int*   maskb = mask + (size_t)b * A_DIM;

  for (int t = threadIdx.x; t < A_DIM; t += NTHR) {
    sx[t]  = posb[3 * t + 0];
    f2 yz; yz.x = posb[3 * t + 1]; yz.y = posb[3 * t + 2];
    syz[t] = yz;
  }
  for (int r = 0; r < A_DIM / NTHR; ++r) {   // 4 rounds
    const int t = r * NTHR + threadIdx.x;
    const unsigned long long bal = __ballot(maskb[t] != 0);
    if ((threadIdx.x & 63) == 0) {
      const int wbase = t >> 5;
      smaskbits[wbase]     = (unsigned)bal;
      smaskbits[wbase + 1] = (unsigned)(bal >> 32);
    }
  }
  __syncthreads();

  const int w    = threadIdx.x >> 6;
  const int lane = threadIdx.x & 63;
  const int i    = list ? list[(size_t)b * A_DIM + s * WPB + w] : s * WPB + w;

  float* orow = out + ((size_t)b * A_DIM + i) * A_DIM;
  const unsigned mi = (smaskbits[i >> 5] >> (i & 31)) & 1u;

  if (mi == 0) {  // masked row -> zeros, wave exits early
    const f4 z = {0.f, 0.f, 0.f, 0.f};
    #pragma unroll
    for (int c = 0; c < 8; ++c)
      *reinterpret_cast<f4*>(orow + (c * 64 + lane) * 4) = z;
    return;
  }

  const float pix = sx[i];
  const f2    piyz = syz[i];

  const int* nrow = nbr + ((size_t)b * A_DIM + i) * A_DIM;

#define LDN(c) (*reinterpret_cast<const int4*>(nrow + ((c) * 64 + lane) * 4))

#define ELEM(nt_, e_, dst_) { \
    const int t_ = (nt_) & (A_DIM - 1); \
    const float xx_ = sx[t_]; \
    const f2 yz_ = syz[t_]; \
    const float dx_ = xx_ - pix; \
    const float dy_ = yz_.x - piyz.x; \
    const float dz_ = yz_.y - piyz.y; \
    const float d2_ = dx_ * dx_ + dy_ * dy_ + dz_ * dz_; \
    const float inv_ = d2_ > 0.0f ? __builtin_amdgcn_rsqf(d2_) : 1e8f; \
    dst_ = ((((wbits >> (bit + e_)) & 1u) != 0u) & (i != j0 + e_)) ? inv_ : 0.0f; }

#define PROC(c, n) { \
    const int j0 = ((c) * 64 + lane) * 4; \
    const unsigned wbits = smaskbits[(c) * 8 + (lane >> 3)]; \
    const int bit = (lane & 7) * 4; \
    f4 r; \
    ELEM(n.x, 0, r.x); \
    ELEM(n.y, 1, r.y); \
    ELEM(n.z, 2, r.z); \
    ELEM(n.w, 3, r.w); \
    *reinterpret_cast<f4*>(orow + j0) = r; }

  // depth-4 rotating prefetch: 4 neighbor int4 loads always in flight
  int4 n0 = LDN(0), n1 = LDN(1), n2 = LDN(2), n3 = LDN(3);
  PROC(0, n0); n0 = LDN(4);
  PROC(1, n1); n1 = LDN(5);
  PROC(2, n2); n2 = LDN(6);
  PROC(3, n3); n3 = LDN(7);
  PROC(4, n0);
  PROC(5, n1);
  PROC(6, n2);
  PROC(7, n3);

#undef PROC
#undef ELEM
#undef LDN
}

extern "C" void kernel_launch(void* const* d_in, const int* in_sizes, int n_in,
                              void* d_out, int out_size, void* d_ws, size_t ws_size,
                              hipStream_t stream) {
  const float* pos  = (const float*)d_in[0];  // [4,2048,3] f32
  const int*   nbr  = (const int*)d_in[1];    // [4,2048,2048] int32
  const int*   mask = (const int*)d_in[2];    // [4,2048] int32 (bool)
  float*       out  = (float*)d_out;          // [4,2048,2048] f32

  const int B = in_sizes[2] / A_DIM;          // 4
  const size_t list_bytes = (size_t)B * A_DIM * sizeof(int);

  int* list = nullptr;
  if (ws_size >= list_bytes) {
    list = (int*)d_ws;
    compact_rows_kernel<<<B, 512, 0, stream>>>(mask, list);
  }

  const int grid = B * (A_DIM / WPB);         // 1024 blocks
  atom_distances_kernel<<<grid, NTHR, 0, stream>>>(pos, nbr, mask, list, out);
}